// Round 19
// baseline (187.152 us; speedup 1.0000x reference)
//
#include <hip/hip_runtime.h>

#define S_LEN 2048
#define D_DIM 1024
#define NH 16
#define HD 64
#define BATCH 2

// 0.125 (1/sqrt(hd)) * log2(e): folded into Wq/bq so QK^T scores are base-2
#define QK_SCALE 0.18033688011112042f
#define LOG2E 1.4426950408889634f

using s16x8 = __attribute__((ext_vector_type(8))) short;
using u16x8 = __attribute__((ext_vector_type(8))) unsigned short;
using f32x4 = __attribute__((ext_vector_type(4))) float;
using bf16x8v = __attribute__((ext_vector_type(8))) __bf16;

typedef const __attribute__((address_space(1))) unsigned int* gas_ptr;
typedef __attribute__((address_space(3))) unsigned int* las_ptr;

__device__ __forceinline__ unsigned short f32_to_bf16(float f) {
  unsigned int u = __float_as_uint(f);
  u += 0x7FFFu + ((u >> 16) & 1u);
  return (unsigned short)(u >> 16);
}

__device__ __forceinline__ f32x4 mfma_bf16(s16x8 a, s16x8 b, f32x4 c) {
  return __builtin_amdgcn_mfma_f32_16x16x32_bf16(
      __builtin_bit_cast(bf16x8v, a), __builtin_bit_cast(bf16x8v, b), c, 0, 0, 0);
}

// v_exp_f32 computes 2^x natively (ISA §3)
__device__ __forceinline__ float exp2_fast(float x) {
  float r;
  asm("v_exp_f32 %0, %1" : "=v"(r) : "v"(x));
  return r;
}

// pack two f32 -> two bf16 in one instruction (lo = a, hi = b)
__device__ __forceinline__ unsigned int cvt_pk_bf16(float a, float b) {
  unsigned int r;
  asm("v_cvt_pk_bf16_f32 %0, %1, %2" : "=v"(r) : "v"(a), "v"(b));
  return r;
}

// ---------------- fused prep: pool+cvt (blocks 0..255) | transpose (256..1023) ---
// pool: 2 batches x 128 chunks of 16 rows; float4 loads, cvt_pk, uint2 stores.
// transpose: 64x64 tiles (256 per matrix); float4 reads -> LDS [64][65] ->
// ushort4 stores.
__global__ __launch_bounds__(256) void prep_kernel(
    const float* __restrict__ hs, unsigned short* __restrict__ hsb,
    float* __restrict__ partial, const float* __restrict__ Wq,
    const float* __restrict__ Wk, const float* __restrict__ Wv,
    unsigned short* __restrict__ WTq, unsigned short* __restrict__ WTk,
    unsigned short* __restrict__ WTv) {
  int bid = blockIdx.x;
  int t = threadIdx.x;
  if (bid < 256) {
    int b = bid >> 7;         // 0..1
    int chunk = bid & 127;    // 16 rows each
    const float* p = hs + ((size_t)b * S_LEN + chunk * 16) * D_DIM + t * 4;
    unsigned short* o = hsb + ((size_t)b * S_LEN + chunk * 16) * D_DIM + t * 4;
    float4 s = {0.f, 0.f, 0.f, 0.f};
    for (int i = 0; i < 16; ++i) {
      float4 v = *(const float4*)(p + (size_t)i * D_DIM);
      s.x += v.x; s.y += v.y; s.z += v.z; s.w += v.w;
      uint2 pk;
      pk.x = cvt_pk_bf16(v.x, v.y);
      pk.y = cvt_pk_bf16(v.z, v.w);
      *(uint2*)(o + (size_t)i * D_DIM) = pk;
    }
    *(float4*)&partial[(size_t)(b * 128 + chunk) * D_DIM + t * 4] = s;
  } else {
    __shared__ float tile[64][65];  // +1 pad: column reads 2-way (free)
    int tb = bid - 256;             // 0..767
    int z = tb >> 8;                // matrix 0..2
    int rem = tb & 255;             // 16x16 grid of 64x64 tiles
    const float* W = (z == 0) ? Wq : (z == 1) ? Wk : Wv;
    unsigned short* WT = (z == 0) ? WTq : (z == 1) ? WTk : WTv;
    float scale = (z == 0) ? QK_SCALE : 1.0f;
    int c0 = (rem & 15) * 64;  // n range
    int r0 = (rem >> 4) * 64;  // k range
    int tx = t & 15, ty = t >> 4;  // tx: 16B slice, ty: 0..15
#pragma unroll
    for (int i = 0; i < 4; ++i) {
      int row = ty + i * 16;  // k-offset
      float4 v = *(const float4*)(W + (size_t)(r0 + row) * D_DIM + c0 + tx * 4);
      tile[row][tx * 4 + 0] = v.x;
      tile[row][tx * 4 + 1] = v.y;
      tile[row][tx * 4 + 2] = v.z;
      tile[row][tx * 4 + 3] = v.w;
    }
    __syncthreads();
#pragma unroll
    for (int jj = 0; jj < 4; ++jj) {
      int n = ty + jj * 16;  // n-offset
      ushort4 pk;
      pk.x = f32_to_bf16(tile[tx * 4 + 0][n] * scale);
      pk.y = f32_to_bf16(tile[tx * 4 + 1][n] * scale);
      pk.z = f32_to_bf16(tile[tx * 4 + 2][n] * scale);
      pk.w = f32_to_bf16(tile[tx * 4 + 3][n] * scale);
      *(ushort4*)&WT[(size_t)(c0 + n) * D_DIM + r0 + tx * 4] = pk;
    }
  }
}

// ---------------- fused reduce + gate (1 block x 1024 threads) -------------------
// Phase 1: 2048 (b,k) columns / 1024 threads = 2 fully-unrolled 128-load chains
// per thread (4 accumulators each -> deep MLP across 16 waves; the R16 trap was
// a ROLLED serial chain). Phase 2/3: the proven MLP/gate logic.
__global__ __launch_bounds__(1024) void gate_fused(
    const float* __restrict__ partial, const float* __restrict__ pW1,
    const float* __restrict__ pb1, const float* __restrict__ gamma,
    const float* __restrict__ beta, const float* __restrict__ mean,
    const float* __restrict__ var, const float* __restrict__ pW2,
    const float* __restrict__ pb2, float* __restrict__ gate) {
  __shared__ float pooled[2 * D_DIM];
  __shared__ float hsh[2][64];
  int t = threadIdx.x;

  // phase 1: reduce 128 chunk-partials per (b,k); thread handles idx = t, t+1024
#pragma unroll
  for (int half = 0; half < 2; ++half) {
    int idx = t + half * 1024;  // 0..2047
    int b = idx >> 10, k = idx & 1023;
    const float* pp = partial + (size_t)b * 128 * D_DIM + k;
    float s0 = 0.f, s1 = 0.f, s2 = 0.f, s3 = 0.f;
#pragma unroll
    for (int c = 0; c < 128; c += 4) {
      s0 += pp[(size_t)(c + 0) * D_DIM];
      s1 += pp[(size_t)(c + 1) * D_DIM];
      s2 += pp[(size_t)(c + 2) * D_DIM];
      s3 += pp[(size_t)(c + 3) * D_DIM];
    }
    pooled[idx] = ((s0 + s1) + (s2 + s3)) * (1.0f / 2048.0f);
  }
  __syncthreads();

  // phase 2: hidden layer (threads 0..511: 4 per (b,j))
  if (t < 512) {
    int b = t >> 8, jj = (t >> 2) & 63, quarter = t & 3;
    float acc = 0.f;
    for (int k = quarter * 256; k < quarter * 256 + 256; ++k)
      acc += pooled[b * D_DIM + k] * pW1[k * 64 + jj];
    acc += __shfl_xor(acc, 1, 64);
    acc += __shfl_xor(acc, 2, 64);
    if (quarter == 0) {
      acc += pb1[jj];
      acc = (acc - mean[jj]) * rsqrtf(var[jj] + 1e-12f) * gamma[jj] + beta[jj];
      hsh[b][jj] = fmaxf(acc, 0.f);
    }
  }
  __syncthreads();

  // phase 3: logits + hard gate
  if (t < 32) {
    int bb = t >> 4, hh = t & 15;
    float lg = pb2[hh];
#pragma unroll
    for (int kk = 0; kk < 64; ++kk) lg += hsh[bb][kk] * pW2[kk * NH + hh];
    gate[bb * NH + hh] = (lg >= 0.f) ? 1.f : 0.f;
  }
}

// ---------------- fused QKV projection GEMM (BK=64, st-swizzled, gate-skip) ------
__global__ __launch_bounds__(256) void proj_gemm3(
    const unsigned short* __restrict__ A, const unsigned short* __restrict__ BT,
    const float* __restrict__ bq, const float* __restrict__ bk,
    const float* __restrict__ bv, const float* __restrict__ gate,
    unsigned short* __restrict__ Qb, unsigned short* __restrict__ Kb,
    unsigned short* __restrict__ Vtb) {
  __shared__ __align__(16) unsigned short As[128 * 64];  // 16 KB, swizzled
  __shared__ __align__(16) unsigned short Bs[128 * 64];  // 16 KB, swizzled
  int idx = blockIdx.x;            // 0..767
  int xcd = idx & 7, j = idx >> 3; // j 0..95
  int xm = xcd * 4 + j / 24;       // m-tile 0..31 (4 per XCD)
  int yn = j % 24;                 // n-tile 0..23
  int m0 = xm * 128, n0 = yn * 128;

  // gate-skip: batch = m0>>11, heads h0,h0+1 = ((n0&1023)>>6) ..
  int gb = m0 >> 11;
  int h0 = (n0 & 1023) >> 6;
  if (gate[gb * NH + h0] == 0.f && gate[gb * NH + h0 + 1] == 0.f) return;

  int tid = threadIdx.x, wave = tid >> 6, lane = tid & 63;
  int l15 = lane & 15, lhi = lane >> 4;
  int wm = (wave >> 1) * 64, wn = (wave & 1) * 64;
  f32x4 acc[4][4] = {};

  const unsigned short* asrc[4];
  const unsigned short* bsrc[4];
  int ldst[4];
#pragma unroll
  for (int r4 = 0; r4 < 4; ++r4) {
    int o = tid * 16 + r4 * 4096;
    int row = o >> 7;
    int e = ((o & 127) ^ ((row & 7) << 4)) >> 1;
    asrc[r4] = A + (size_t)(m0 + row) * D_DIM + e;
    bsrc[r4] = BT + (size_t)(n0 + row) * D_DIM + e;
    ldst[r4] = o >> 1;
  }
  int rsw = (l15 & 7) << 4;

  for (int k0 = 0; k0 < D_DIM; k0 += 64) {
#pragma unroll
    for (int r4 = 0; r4 < 4; ++r4) {
      __builtin_amdgcn_global_load_lds((gas_ptr)(asrc[r4] + k0),
                                       (las_ptr)(As + ldst[r4]), 16, 0, 0);
      __builtin_amdgcn_global_load_lds((gas_ptr)(bsrc[r4] + k0),
                                       (las_ptr)(Bs + ldst[r4]), 16, 0, 0);
    }
    __syncthreads();
    __builtin_amdgcn_s_setprio(1);
#pragma unroll
    for (int ks = 0; ks < 2; ++ks) {
      s16x8 af[4], bf[4];
#pragma unroll
      for (int mi = 0; mi < 4; ++mi)
        af[mi] = *(const s16x8*)((const char*)As + (wm + mi * 16 + l15) * 128 +
                                 ((ks * 64 + lhi * 16) ^ rsw));
#pragma unroll
      for (int ni = 0; ni < 4; ++ni)
        bf[ni] = *(const s16x8*)((const char*)Bs + (wn + ni * 16 + l15) * 128 +
                                 ((ks * 64 + lhi * 16) ^ rsw));
#pragma unroll
      for (int mi = 0; mi < 4; ++mi)
#pragma unroll
        for (int ni = 0; ni < 4; ++ni)
          acc[mi][ni] = mfma_bf16(af[mi], bf[ni], acc[mi][ni]);
    }
    __builtin_amdgcn_s_setprio(0);
    __syncthreads();
  }

#pragma unroll
  for (int mi = 0; mi < 4; ++mi)
#pragma unroll
    for (int ni = 0; ni < 4; ++ni) {
      int row0 = m0 + wm + mi * 16 + lhi * 4;
      int col = n0 + wn + ni * 16 + l15;
      int seg = col >> 10, c = col & 1023;
      if (seg == 2) {
        float bvv = bv[c];
        int h = c >> 6, d = c & 63;
        int b = row0 >> 11, s = row0 & 2047;
        ushort4 pk;
        pk.x = f32_to_bf16(acc[mi][ni][0] + bvv);
        pk.y = f32_to_bf16(acc[mi][ni][1] + bvv);
        pk.z = f32_to_bf16(acc[mi][ni][2] + bvv);
        pk.w = f32_to_bf16(acc[mi][ni][3] + bvv);
        *(ushort4*)&Vtb[((size_t)(b * NH + h) * HD + d) * S_LEN + s] = pk;
      } else {
        float bb2 = (seg == 0) ? bq[c] * QK_SCALE : bk[c];
        unsigned short* dst = (seg == 0) ? Qb : Kb;
        int h = c >> 6, d = c & 63;
#pragma unroll
        for (int r = 0; r < 4; ++r) {
          int row = row0 + r;
          int b = row >> 11, s = row & 2047;
          dst[((size_t)(b * NH + h) * S_LEN + s) * HD + d] =
              f32_to_bf16(acc[mi][ni][r] + bb2);
        }
      }
    }
}

// ---------------- flash attention: R11 structure + static-scale softmax ----------
// (exact R11 kernel — measured 56 us; all structural deviations R12-R15 regressed)
__global__ __launch_bounds__(256) void attn_kernel(
    const unsigned short* __restrict__ Q, const unsigned short* __restrict__ K,
    const unsigned short* __restrict__ Vt, const float* __restrict__ mask,
    const float* __restrict__ gate, float* __restrict__ Out) {
  __shared__ __align__(16) unsigned short Ks[2][4096];     // [key][d], swizzled
  __shared__ __align__(16) unsigned short Vs[2][4096];     // [d][key], swizzled
  __shared__ __align__(16) unsigned short p_lds[4][1024];  // per-wave [q][key]

  int idx = blockIdx.x;
  int xcd = idx & 7;
  int slot = idx >> 3;
  int qc = slot & 31;
  int r = (slot >> 5) * 8 + xcd;  // rank 0..31
  int tid = threadIdx.x;
  int wave = tid >> 6, lane = tid & 63;
  int l15 = lane & 15, lhi = lane >> 4;

  // ballot the gate vector (uniform across waves)
  float gv = (lane < 32) ? gate[lane] : 0.f;
  unsigned long long live = __ballot(gv != 0.f);
  int W = __popcll(live);
  bool working = (r < W);
  int want = working ? r : (r - W);
  unsigned long long M = working ? live : (~live & 0xFFFFFFFFull);
  int head = 0, c = 0;
#pragma unroll
  for (int hh = 0; hh < 32; ++hh) {
    if ((M >> hh) & 1) {
      if (c == want) head = hh;
      ++c;
    }
  }
  int b = head >> 4, h = head & 15;
  int q0 = qc * 64 + wave * 16;
  int qrow = q0 + l15;

  if (!working) {
    float4 z = {0.f, 0.f, 0.f, 0.f};
    int row = qc * 64 + (tid >> 2);
    float* op = Out + ((size_t)b * S_LEN + row) * D_DIM + h * HD + (tid & 3) * 16;
#pragma unroll
    for (int dd = 0; dd < 4; ++dd) *(float4*)(op + dd * 4) = z;
    return;
  }

  const unsigned short* Qp = Q + (size_t)head * S_LEN * HD;
  const unsigned short* Kp = K + (size_t)head * S_LEN * HD;
  const unsigned short* Vp = Vt + (size_t)head * HD * S_LEN;
  const float* maskp = mask + (size_t)b * S_LEN;

  int psw = (l15 & 7) << 4;
  int oo0 = wave * 2048 + lane * 16;
  int oo1 = oo0 + 1024;
  int row0 = oo0 >> 7, row1 = oo1 >> 7;
  int e0 = ((oo0 & 127) ^ ((row0 & 7) << 4)) >> 1;
  int e1 = ((oo1 & 127) ^ ((row1 & 7) << 4)) >> 1;
  const unsigned short* kb0 = Kp + row0 * HD + e0;
  const unsigned short* kb1 = Kp + row1 * HD + e1;
  const unsigned short* vb0 = Vp + (size_t)row0 * S_LEN + e0;
  const unsigned short* vb1 = Vp + (size_t)row1 * S_LEN + e1;
  unsigned short* ksb = &Ks[0][0];
  unsigned short* vsb = &Vs[0][0];
  int w0 = (wave * 2048) >> 1;
  int w1 = w0 + 512;

#define STAGE(BUFI, KTV)                                                            \
  {                                                                                 \
    __builtin_amdgcn_global_load_lds((gas_ptr)(kb0 + (size_t)(KTV) * HD),           \
                                     (las_ptr)(ksb + (BUFI) * 4096 + w0), 16, 0, 0);\
    __builtin_amdgcn_global_load_lds((gas_ptr)(kb1 + (size_t)(KTV) * HD),           \
                                     (las_ptr)(ksb + (BUFI) * 4096 + w1), 16, 0, 0);\
    __builtin_amdgcn_global_load_lds((gas_ptr)(vb0 + (KTV)),                        \
                                     (las_ptr)(vsb + (BUFI) * 4096 + w0), 16, 0, 0);\
    __builtin_amdgcn_global_load_lds((gas_ptr)(vb1 + (KTV)),                        \
                                     (las_ptr)(vsb + (BUFI) * 4096 + w1), 16, 0, 0);\
  }

  STAGE(0, 0);
  float4 mvc[4];
#pragma unroll
  for (int nf = 0; nf < 4; ++nf)
    mvc[nf] = *(const float4*)(maskp + nf * 16 + lhi * 4);

  s16x8 q_frag[2];
#pragma unroll
  for (int ks = 0; ks < 2; ++ks)
    q_frag[ks] = *(const s16x8*)(Qp + (size_t)qrow * HD + ks * 32 + lhi * 8);

  int swz0 = (lhi * 16) ^ psw;        // ks=0
  int swz1 = (64 + lhi * 16) ^ psw;   // ks=1
  char* pbase = (char*)p_lds + wave * 2048 + l15 * 128;

  f32x4 o_acc[4] = {};
  float s_run = 0.f;

  __syncthreads();  // tile 0 staged & visible; mvc resident

  for (int kt = 0; kt < S_LEN; kt += 64) {
    int buf = (kt >> 6) & 1;
    int ktn = (kt + 64) & (S_LEN - 1);  // last iter wraps harmlessly
    STAGE(buf ^ 1, ktn);                // next-tile DMA: drained only by barrier
    float4 mvn[4];                      // next-tile mask (same drain)
#pragma unroll
    for (int nf = 0; nf < 4; ++nf)
      mvn[nf] = *(const float4*)(maskp + ktn + nf * 16 + lhi * 4);

    // ---- QK^T from LDS: sc[nf][rr] = S[q=l15][key=nf*16+lhi*4+rr] (base-2)
    const char* kc = (const char*)ksb + buf * 8192;
    f32x4 sc[4] = {};
    __builtin_amdgcn_s_setprio(1);
#pragma unroll
    for (int nf = 0; nf < 4; ++nf) {
      int rb = (nf * 16 + l15) * 128;
      s16x8 a0 = *(const s16x8*)(kc + (rb + swz0));
      s16x8 a1 = *(const s16x8*)(kc + (rb + swz1));
      sc[nf] = mfma_bf16(a0, q_frag[0], sc[nf]);
      sc[nf] = mfma_bf16(a1, q_frag[1], sc[nf]);
    }
    __builtin_amdgcn_s_setprio(0);

    // ---- static-scale softmax: P = 2^(s + mask*log2e); per-lane partial sums
    float psnf[4];
#pragma unroll
    for (int nf = 0; nf < 4; ++nf) {
#pragma unroll
      for (int rr = 0; rr < 4; ++rr)
        sc[nf][rr] = exp2_fast(fmaf(((const float*)&mvc[nf])[rr], LOG2E, sc[nf][rr]));
      psnf[nf] = (sc[nf][0] + sc[nf][1]) + (sc[nf][2] + sc[nf][3]);
    }
    s_run += (psnf[0] + psnf[1]) + (psnf[2] + psnf[3]);

    // ---- P -> per-wave LDS slice (cvt_pk; swizzled; wave-local ordering)
#pragma unroll
    for (int nf = 0; nf < 4; ++nf) {
      uint2 pk;
      pk.x = cvt_pk_bf16(sc[nf][0], sc[nf][1]);
      pk.y = cvt_pk_bf16(sc[nf][2], sc[nf][3]);
      *(uint2*)(pbase + ((nf * 32 + lhi * 8) ^ psw)) = pk;
    }

    // ---- O^T += V^T · P^T from LDS (swizzled reads)
    const char* vc = (const char*)vsb + buf * 8192;
    __builtin_amdgcn_s_setprio(1);
#pragma unroll
    for (int ks = 0; ks < 2; ++ks) {
      int sw = ks ? swz1 : swz0;
      s16x8 pf = *(const s16x8*)(pbase + ((ks * 64 + lhi * 16) ^ psw));
#pragma unroll
      for (int df = 0; df < 4; ++df) {
        s16x8 vf = *(const s16x8*)(vc + ((df * 16 + l15) * 128 + sw));
        o_acc[df] = mfma_bf16(vf, pf, o_acc[df]);
      }
    }
    __builtin_amdgcn_s_setprio(0);

    __syncthreads();  // drains DMA+mask loads; WAR fence on buf/p_lds
#pragma unroll
    for (int nf = 0; nf < 4; ++nf) mvc[nf] = mvn[nf];
  }
#undef STAGE

  // merge the 4 lhi-groups' partial sums (once per block)
  float s_tot = s_run;
  s_tot += __shfl_xor(s_tot, 16, 64);
  s_tot += __shfl_xor(s_tot, 32, 64);
  float inv = 1.0f / s_tot;

#pragma unroll
  for (int df = 0; df < 4; ++df) {
    float4 ov;
    ov.x = o_acc[df][0] * inv;
    ov.y = o_acc[df][1] * inv;
    ov.z = o_acc[df][2] * inv;
    ov.w = o_acc[df][3] * inv;
    *(float4*)(Out + ((size_t)b * S_LEN + qrow) * D_DIM + h * HD + df * 16 + lhi * 4) = ov;
  }
}

// ---------------- launch ----------------

extern "C" void kernel_launch(void* const* d_in, const int* in_sizes, int n_in,
                              void* d_out, int out_size, void* d_ws, size_t ws_size,
                              hipStream_t stream) {
  (void)in_sizes; (void)n_in; (void)out_size; (void)ws_size;
  const float* hs   = (const float*)d_in[0];
  const float* mask = (const float*)d_in[1];
  const float* Wq   = (const float*)d_in[2];
  const float* bq   = (const float*)d_in[3];
  const float* Wk   = (const float*)d_in[4];
  const float* bk   = (const float*)d_in[5];
  const float* Wv   = (const float*)d_in[6];
  const float* bv   = (const float*)d_in[7];
  const float* pW1  = (const float*)d_in[8];
  const float* pb1  = (const float*)d_in[9];
  const float* gam  = (const float*)d_in[10];
  const float* bet  = (const float*)d_in[11];
  const float* mea  = (const float*)d_in[12];
  const float* var  = (const float*)d_in[13];
  const float* pW2  = (const float*)d_in[14];
  const float* pb2  = (const float*)d_in[15];
  float* out = (float*)d_out;

  const size_t MB = 1u << 20;
  char* ws = (char*)d_ws;
  unsigned short* hsb = (unsigned short*)(ws);            // 8 MB [4096][1024]
  unsigned short* wTq = (unsigned short*)(ws + 8 * MB);   // 2 MB  (wTq|wTk|wTv
  unsigned short* wTk = (unsigned short*)(ws + 10 * MB);  // 2 MB   must stay
  unsigned short* wTv = (unsigned short*)(ws + 12 * MB);  // 2 MB   contiguous!)
  unsigned short* Qb  = (unsigned short*)(ws + 14 * MB);  // 8 MB [32][2048][64]
  unsigned short* Kb  = (unsigned short*)(ws + 22 * MB);  // 8 MB [32][2048][64]
  unsigned short* Vtb = (unsigned short*)(ws + 30 * MB);  // 8 MB [32][64][2048]
  float* partial = (float*)(ws + 38 * MB);                // 1 MB [2*128][1024]
  float* gateb   = (float*)(ws + 39 * MB);                // 128 B [32]

  // fused pool+cvt (256 blocks) | weight transpose (768 blocks) — independent
  prep_kernel<<<1024, 256, 0, stream>>>(hs, hsb, partial, Wq, Wk, Wv, wTq, wTk, wTv);
  // fused chunk-reduce + gate MLP (1 block x 1024 threads)
  gate_fused<<<1, 1024, 0, stream>>>(partial, pW1, pb1, gam, bet, mea, var, pW2, pb2, gateb);

  // fused Q+K+V projection with gate-skip: N = 3072 over [wTq|wTk|wTv]
  proj_gemm3<<<768, 256, 0, stream>>>(hsb, wTq, bq, bk, bv, gateb, Qb, Kb, Vtb);

  attn_kernel<<<1024, 256, 0, stream>>>(Qb, Kb, Vtb, mask, gateb, out);
}

// Round 20
// 123.877 us; speedup vs baseline: 1.5108x; 1.5108x over previous
//
#include <hip/hip_runtime.h>

#define S_LEN 2048
#define D_DIM 1024
#define NH 16
#define HD 64
#define BATCH 2

// 0.125 (1/sqrt(hd)) * log2(e): folded into Wq/bq so QK^T scores are base-2
#define QK_SCALE 0.18033688011112042f
#define LOG2E 1.4426950408889634f

using s16x8 = __attribute__((ext_vector_type(8))) short;
using u16x8 = __attribute__((ext_vector_type(8))) unsigned short;
using f32x4 = __attribute__((ext_vector_type(4))) float;
using bf16x8v = __attribute__((ext_vector_type(8))) __bf16;

typedef const __attribute__((address_space(1))) unsigned int* gas_ptr;
typedef __attribute__((address_space(3))) unsigned int* las_ptr;

__device__ __forceinline__ unsigned short f32_to_bf16(float f) {
  unsigned int u = __float_as_uint(f);
  u += 0x7FFFu + ((u >> 16) & 1u);
  return (unsigned short)(u >> 16);
}

__device__ __forceinline__ f32x4 mfma_bf16(s16x8 a, s16x8 b, f32x4 c) {
  return __builtin_amdgcn_mfma_f32_16x16x32_bf16(
      __builtin_bit_cast(bf16x8v, a), __builtin_bit_cast(bf16x8v, b), c, 0, 0, 0);
}

// v_exp_f32 computes 2^x natively (ISA §3)
__device__ __forceinline__ float exp2_fast(float x) {
  float r;
  asm("v_exp_f32 %0, %1" : "=v"(r) : "v"(x));
  return r;
}

// pack two f32 -> two bf16 in one instruction (lo = a, hi = b)
__device__ __forceinline__ unsigned int cvt_pk_bf16(float a, float b) {
  unsigned int r;
  asm("v_cvt_pk_bf16_f32 %0, %1, %2" : "=v"(r) : "v"(a), "v"(b));
  return r;
}

// ---------------- fused prep: pool+cvt (blocks 0..255) | transpose (256..1023) ---
// pool: 2 batches x 128 chunks of 16 rows; float4 loads, cvt_pk, uint2 stores.
// transpose: 64x64 tiles (256 per matrix); float4 reads -> LDS [64][65] ->
// ushort4 stores.
__global__ __launch_bounds__(256) void prep_kernel(
    const float* __restrict__ hs, unsigned short* __restrict__ hsb,
    float* __restrict__ partial, const float* __restrict__ Wq,
    const float* __restrict__ Wk, const float* __restrict__ Wv,
    unsigned short* __restrict__ WTq, unsigned short* __restrict__ WTk,
    unsigned short* __restrict__ WTv) {
  int bid = blockIdx.x;
  int t = threadIdx.x;
  if (bid < 256) {
    int b = bid >> 7;         // 0..1
    int chunk = bid & 127;    // 16 rows each
    const float* p = hs + ((size_t)b * S_LEN + chunk * 16) * D_DIM + t * 4;
    unsigned short* o = hsb + ((size_t)b * S_LEN + chunk * 16) * D_DIM + t * 4;
    float4 s = {0.f, 0.f, 0.f, 0.f};
    for (int i = 0; i < 16; ++i) {
      float4 v = *(const float4*)(p + (size_t)i * D_DIM);
      s.x += v.x; s.y += v.y; s.z += v.z; s.w += v.w;
      uint2 pk;
      pk.x = cvt_pk_bf16(v.x, v.y);
      pk.y = cvt_pk_bf16(v.z, v.w);
      *(uint2*)(o + (size_t)i * D_DIM) = pk;
    }
    *(float4*)&partial[(size_t)(b * 128 + chunk) * D_DIM + t * 4] = s;
  } else {
    __shared__ float tile[64][65];  // +1 pad: column reads 2-way (free)
    int tb = bid - 256;             // 0..767
    int z = tb >> 8;                // matrix 0..2
    int rem = tb & 255;             // 16x16 grid of 64x64 tiles
    const float* W = (z == 0) ? Wq : (z == 1) ? Wk : Wv;
    unsigned short* WT = (z == 0) ? WTq : (z == 1) ? WTk : WTv;
    float scale = (z == 0) ? QK_SCALE : 1.0f;
    int c0 = (rem & 15) * 64;  // n range
    int r0 = (rem >> 4) * 64;  // k range
    int tx = t & 15, ty = t >> 4;  // tx: 16B slice, ty: 0..15
#pragma unroll
    for (int i = 0; i < 4; ++i) {
      int row = ty + i * 16;  // k-offset
      float4 v = *(const float4*)(W + (size_t)(r0 + row) * D_DIM + c0 + tx * 4);
      tile[row][tx * 4 + 0] = v.x;
      tile[row][tx * 4 + 1] = v.y;
      tile[row][tx * 4 + 2] = v.z;
      tile[row][tx * 4 + 3] = v.w;
    }
    __syncthreads();
#pragma unroll
    for (int jj = 0; jj < 4; ++jj) {
      int n = ty + jj * 16;  // n-offset
      ushort4 pk;
      pk.x = f32_to_bf16(tile[tx * 4 + 0][n] * scale);
      pk.y = f32_to_bf16(tile[tx * 4 + 1][n] * scale);
      pk.z = f32_to_bf16(tile[tx * 4 + 2][n] * scale);
      pk.w = f32_to_bf16(tile[tx * 4 + 3][n] * scale);
      *(ushort4*)&WT[(size_t)(c0 + n) * D_DIM + r0 + tx * 4] = pk;
    }
  }
}

// ---------------- chunk-reduce: pooled[b][k] = sum_c partial[b][c][k] / 2048 -----
// 16 blocks x 128 threads = one thread per (b,k); 128 independent loads fully
// unrolled into 4 accumulators (ample VGPR headroom at 128 thr/block — the R19
// fusion starved this of VGPRs and serialized 256 x 700cyc).
__global__ __launch_bounds__(128) void pool_reduce(const float* __restrict__ partial,
                                                   float* __restrict__ pooled) {
  int idx = blockIdx.x * 128 + threadIdx.x;  // 0..2047
  int b = idx >> 10, k = idx & 1023;
  const float* pp = partial + (size_t)b * 128 * D_DIM + k;
  float s0 = 0.f, s1 = 0.f, s2 = 0.f, s3 = 0.f;
#pragma unroll
  for (int c = 0; c < 128; c += 4) {
    s0 += pp[(size_t)(c + 0) * D_DIM];
    s1 += pp[(size_t)(c + 1) * D_DIM];
    s2 += pp[(size_t)(c + 2) * D_DIM];
    s3 += pp[(size_t)(c + 3) * D_DIM];
  }
  pooled[idx] = ((s0 + s1) + (s2 + s3)) * (1.0f / 2048.0f);
}

// ---------------- gate (reads pre-reduced pooled[2048]) ----------------
__global__ __launch_bounds__(512) void gate_kernel(
    const float* __restrict__ pooled_g, const float* __restrict__ pW1,
    const float* __restrict__ pb1, const float* __restrict__ gamma,
    const float* __restrict__ beta, const float* __restrict__ mean,
    const float* __restrict__ var, const float* __restrict__ pW2,
    const float* __restrict__ pb2, float* __restrict__ gate) {
  __shared__ float pooled[2 * D_DIM];
  __shared__ float hsh[2][64];
  int t = threadIdx.x;
  for (int idx = t; idx < 2 * D_DIM; idx += 512) pooled[idx] = pooled_g[idx];
  __syncthreads();
  int b = t >> 8, jj = (t >> 2) & 63, quarter = t & 3;
  float acc = 0.f;
  for (int k = quarter * 256; k < quarter * 256 + 256; ++k)
    acc += pooled[b * D_DIM + k] * pW1[k * 64 + jj];
  acc += __shfl_xor(acc, 1, 64);
  acc += __shfl_xor(acc, 2, 64);
  if (quarter == 0) {
    acc += pb1[jj];
    acc = (acc - mean[jj]) * rsqrtf(var[jj] + 1e-12f) * gamma[jj] + beta[jj];
    hsh[b][jj] = fmaxf(acc, 0.f);
  }
  __syncthreads();
  if (t < 32) {
    int bb = t >> 4, hh = t & 15;
    float lg = pb2[hh];
#pragma unroll
    for (int kk = 0; kk < 64; ++kk) lg += hsh[bb][kk] * pW2[kk * NH + hh];
    gate[bb * NH + hh] = (lg >= 0.f) ? 1.f : 0.f;
  }
}

// ---------------- fused QKV projection GEMM (BK=64, st-swizzled, gate-skip) ------
__global__ __launch_bounds__(256) void proj_gemm3(
    const unsigned short* __restrict__ A, const unsigned short* __restrict__ BT,
    const float* __restrict__ bq, const float* __restrict__ bk,
    const float* __restrict__ bv, const float* __restrict__ gate,
    unsigned short* __restrict__ Qb, unsigned short* __restrict__ Kb,
    unsigned short* __restrict__ Vtb) {
  __shared__ __align__(16) unsigned short As[128 * 64];  // 16 KB, swizzled
  __shared__ __align__(16) unsigned short Bs[128 * 64];  // 16 KB, swizzled
  int idx = blockIdx.x;            // 0..767
  int xcd = idx & 7, j = idx >> 3; // j 0..95
  int xm = xcd * 4 + j / 24;       // m-tile 0..31 (4 per XCD)
  int yn = j % 24;                 // n-tile 0..23
  int m0 = xm * 128, n0 = yn * 128;

  // gate-skip: batch = m0>>11, heads h0,h0+1 = ((n0&1023)>>6) ..
  int gb = m0 >> 11;
  int h0 = (n0 & 1023) >> 6;
  if (gate[gb * NH + h0] == 0.f && gate[gb * NH + h0 + 1] == 0.f) return;

  int tid = threadIdx.x, wave = tid >> 6, lane = tid & 63;
  int l15 = lane & 15, lhi = lane >> 4;
  int wm = (wave >> 1) * 64, wn = (wave & 1) * 64;
  f32x4 acc[4][4] = {};

  const unsigned short* asrc[4];
  const unsigned short* bsrc[4];
  int ldst[4];
#pragma unroll
  for (int r4 = 0; r4 < 4; ++r4) {
    int o = tid * 16 + r4 * 4096;
    int row = o >> 7;
    int e = ((o & 127) ^ ((row & 7) << 4)) >> 1;
    asrc[r4] = A + (size_t)(m0 + row) * D_DIM + e;
    bsrc[r4] = BT + (size_t)(n0 + row) * D_DIM + e;
    ldst[r4] = o >> 1;
  }
  int rsw = (l15 & 7) << 4;

  for (int k0 = 0; k0 < D_DIM; k0 += 64) {
#pragma unroll
    for (int r4 = 0; r4 < 4; ++r4) {
      __builtin_amdgcn_global_load_lds((gas_ptr)(asrc[r4] + k0),
                                       (las_ptr)(As + ldst[r4]), 16, 0, 0);
      __builtin_amdgcn_global_load_lds((gas_ptr)(bsrc[r4] + k0),
                                       (las_ptr)(Bs + ldst[r4]), 16, 0, 0);
    }
    __syncthreads();
    __builtin_amdgcn_s_setprio(1);
#pragma unroll
    for (int ks = 0; ks < 2; ++ks) {
      s16x8 af[4], bf[4];
#pragma unroll
      for (int mi = 0; mi < 4; ++mi)
        af[mi] = *(const s16x8*)((const char*)As + (wm + mi * 16 + l15) * 128 +
                                 ((ks * 64 + lhi * 16) ^ rsw));
#pragma unroll
      for (int ni = 0; ni < 4; ++ni)
        bf[ni] = *(const s16x8*)((const char*)Bs + (wn + ni * 16 + l15) * 128 +
                                 ((ks * 64 + lhi * 16) ^ rsw));
#pragma unroll
      for (int mi = 0; mi < 4; ++mi)
#pragma unroll
        for (int ni = 0; ni < 4; ++ni)
          acc[mi][ni] = mfma_bf16(af[mi], bf[ni], acc[mi][ni]);
    }
    __builtin_amdgcn_s_setprio(0);
    __syncthreads();
  }

#pragma unroll
  for (int mi = 0; mi < 4; ++mi)
#pragma unroll
    for (int ni = 0; ni < 4; ++ni) {
      int row0 = m0 + wm + mi * 16 + lhi * 4;
      int col = n0 + wn + ni * 16 + l15;
      int seg = col >> 10, c = col & 1023;
      if (seg == 2) {
        float bvv = bv[c];
        int h = c >> 6, d = c & 63;
        int b = row0 >> 11, s = row0 & 2047;
        ushort4 pk;
        pk.x = f32_to_bf16(acc[mi][ni][0] + bvv);
        pk.y = f32_to_bf16(acc[mi][ni][1] + bvv);
        pk.z = f32_to_bf16(acc[mi][ni][2] + bvv);
        pk.w = f32_to_bf16(acc[mi][ni][3] + bvv);
        *(ushort4*)&Vtb[((size_t)(b * NH + h) * HD + d) * S_LEN + s] = pk;
      } else {
        float bb2 = (seg == 0) ? bq[c] * QK_SCALE : bk[c];
        unsigned short* dst = (seg == 0) ? Qb : Kb;
        int h = c >> 6, d = c & 63;
#pragma unroll
        for (int r = 0; r < 4; ++r) {
          int row = row0 + r;
          int b = row >> 11, s = row & 2047;
          dst[((size_t)(b * NH + h) * S_LEN + s) * HD + d] =
              f32_to_bf16(acc[mi][ni][r] + bb2);
        }
      }
    }
}

// ---------------- flash attention: R11 structure + static-scale softmax ----------
// (exact R11 kernel — measured 56 us; all structural deviations R12-R15 regressed)
__global__ __launch_bounds__(256) void attn_kernel(
    const unsigned short* __restrict__ Q, const unsigned short* __restrict__ K,
    const unsigned short* __restrict__ Vt, const float* __restrict__ mask,
    const float* __restrict__ gate, float* __restrict__ Out) {
  __shared__ __align__(16) unsigned short Ks[2][4096];     // [key][d], swizzled
  __shared__ __align__(16) unsigned short Vs[2][4096];     // [d][key], swizzled
  __shared__ __align__(16) unsigned short p_lds[4][1024];  // per-wave [q][key]

  int idx = blockIdx.x;
  int xcd = idx & 7;
  int slot = idx >> 3;
  int qc = slot & 31;
  int r = (slot >> 5) * 8 + xcd;  // rank 0..31
  int tid = threadIdx.x;
  int wave = tid >> 6, lane = tid & 63;
  int l15 = lane & 15, lhi = lane >> 4;

  // ballot the gate vector (uniform across waves)
  float gv = (lane < 32) ? gate[lane] : 0.f;
  unsigned long long live = __ballot(gv != 0.f);
  int W = __popcll(live);
  bool working = (r < W);
  int want = working ? r : (r - W);
  unsigned long long M = working ? live : (~live & 0xFFFFFFFFull);
  int head = 0, c = 0;
#pragma unroll
  for (int hh = 0; hh < 32; ++hh) {
    if ((M >> hh) & 1) {
      if (c == want) head = hh;
      ++c;
    }
  }
  int b = head >> 4, h = head & 15;
  int q0 = qc * 64 + wave * 16;
  int qrow = q0 + l15;

  if (!working) {
    float4 z = {0.f, 0.f, 0.f, 0.f};
    int row = qc * 64 + (tid >> 2);
    float* op = Out + ((size_t)b * S_LEN + row) * D_DIM + h * HD + (tid & 3) * 16;
#pragma unroll
    for (int dd = 0; dd < 4; ++dd) *(float4*)(op + dd * 4) = z;
    return;
  }

  const unsigned short* Qp = Q + (size_t)head * S_LEN * HD;
  const unsigned short* Kp = K + (size_t)head * S_LEN * HD;
  const unsigned short* Vp = Vt + (size_t)head * HD * S_LEN;
  const float* maskp = mask + (size_t)b * S_LEN;

  int psw = (l15 & 7) << 4;
  int oo0 = wave * 2048 + lane * 16;
  int oo1 = oo0 + 1024;
  int row0 = oo0 >> 7, row1 = oo1 >> 7;
  int e0 = ((oo0 & 127) ^ ((row0 & 7) << 4)) >> 1;
  int e1 = ((oo1 & 127) ^ ((row1 & 7) << 4)) >> 1;
  const unsigned short* kb0 = Kp + row0 * HD + e0;
  const unsigned short* kb1 = Kp + row1 * HD + e1;
  const unsigned short* vb0 = Vp + (size_t)row0 * S_LEN + e0;
  const unsigned short* vb1 = Vp + (size_t)row1 * S_LEN + e1;
  unsigned short* ksb = &Ks[0][0];
  unsigned short* vsb = &Vs[0][0];
  int w0 = (wave * 2048) >> 1;
  int w1 = w0 + 512;

#define STAGE(BUFI, KTV)                                                            \
  {                                                                                 \
    __builtin_amdgcn_global_load_lds((gas_ptr)(kb0 + (size_t)(KTV) * HD),           \
                                     (las_ptr)(ksb + (BUFI) * 4096 + w0), 16, 0, 0);\
    __builtin_amdgcn_global_load_lds((gas_ptr)(kb1 + (size_t)(KTV) * HD),           \
                                     (las_ptr)(ksb + (BUFI) * 4096 + w1), 16, 0, 0);\
    __builtin_amdgcn_global_load_lds((gas_ptr)(vb0 + (KTV)),                        \
                                     (las_ptr)(vsb + (BUFI) * 4096 + w0), 16, 0, 0);\
    __builtin_amdgcn_global_load_lds((gas_ptr)(vb1 + (KTV)),                        \
                                     (las_ptr)(vsb + (BUFI) * 4096 + w1), 16, 0, 0);\
  }

  STAGE(0, 0);
  float4 mvc[4];
#pragma unroll
  for (int nf = 0; nf < 4; ++nf)
    mvc[nf] = *(const float4*)(maskp + nf * 16 + lhi * 4);

  s16x8 q_frag[2];
#pragma unroll
  for (int ks = 0; ks < 2; ++ks)
    q_frag[ks] = *(const s16x8*)(Qp + (size_t)qrow * HD + ks * 32 + lhi * 8);

  int swz0 = (lhi * 16) ^ psw;        // ks=0
  int swz1 = (64 + lhi * 16) ^ psw;   // ks=1
  char* pbase = (char*)p_lds + wave * 2048 + l15 * 128;

  f32x4 o_acc[4] = {};
  float s_run = 0.f;

  __syncthreads();  // tile 0 staged & visible; mvc resident

  for (int kt = 0; kt < S_LEN; kt += 64) {
    int buf = (kt >> 6) & 1;
    int ktn = (kt + 64) & (S_LEN - 1);  // last iter wraps harmlessly
    STAGE(buf ^ 1, ktn);                // next-tile DMA: drained only by barrier
    float4 mvn[4];                      // next-tile mask (same drain)
#pragma unroll
    for (int nf = 0; nf < 4; ++nf)
      mvn[nf] = *(const float4*)(maskp + ktn + nf * 16 + lhi * 4);

    // ---- QK^T from LDS: sc[nf][rr] = S[q=l15][key=nf*16+lhi*4+rr] (base-2)
    const char* kc = (const char*)ksb + buf * 8192;
    f32x4 sc[4] = {};
    __builtin_amdgcn_s_setprio(1);
#pragma unroll
    for (int nf = 0; nf < 4; ++nf) {
      int rb = (nf * 16 + l15) * 128;
      s16x8 a0 = *(const s16x8*)(kc + (rb + swz0));
      s16x8 a1 = *(const s16x8*)(kc + (rb + swz1));
      sc[nf] = mfma_bf16(a0, q_frag[0], sc[nf]);
      sc[nf] = mfma_bf16(a1, q_frag[1], sc[nf]);
    }
    __builtin_amdgcn_s_setprio(0);

    // ---- static-scale softmax: P = 2^(s + mask*log2e); per-lane partial sums
    float psnf[4];
#pragma unroll
    for (int nf = 0; nf < 4; ++nf) {
#pragma unroll
      for (int rr = 0; rr < 4; ++rr)
        sc[nf][rr] = exp2_fast(fmaf(((const float*)&mvc[nf])[rr], LOG2E, sc[nf][rr]));
      psnf[nf] = (sc[nf][0] + sc[nf][1]) + (sc[nf][2] + sc[nf][3]);
    }
    s_run += (psnf[0] + psnf[1]) + (psnf[2] + psnf[3]);

    // ---- P -> per-wave LDS slice (cvt_pk; swizzled; wave-local ordering)
#pragma unroll
    for (int nf = 0; nf < 4; ++nf) {
      uint2 pk;
      pk.x = cvt_pk_bf16(sc[nf][0], sc[nf][1]);
      pk.y = cvt_pk_bf16(sc[nf][2], sc[nf][3]);
      *(uint2*)(pbase + ((nf * 32 + lhi * 8) ^ psw)) = pk;
    }

    // ---- O^T += V^T · P^T from LDS (swizzled reads)
    const char* vc = (const char*)vsb + buf * 8192;
    __builtin_amdgcn_s_setprio(1);
#pragma unroll
    for (int ks = 0; ks < 2; ++ks) {
      int sw = ks ? swz1 : swz0;
      s16x8 pf = *(const s16x8*)(pbase + ((ks * 64 + lhi * 16) ^ psw));
#pragma unroll
      for (int df = 0; df < 4; ++df) {
        s16x8 vf = *(const s16x8*)(vc + ((df * 16 + l15) * 128 + sw));
        o_acc[df] = mfma_bf16(vf, pf, o_acc[df]);
      }
    }
    __builtin_amdgcn_s_setprio(0);

    __syncthreads();  // drains DMA+mask loads; WAR fence on buf/p_lds
#pragma unroll
    for (int nf = 0; nf < 4; ++nf) mvc[nf] = mvn[nf];
  }
#undef STAGE

  // merge the 4 lhi-groups' partial sums (once per block)
  float s_tot = s_run;
  s_tot += __shfl_xor(s_tot, 16, 64);
  s_tot += __shfl_xor(s_tot, 32, 64);
  float inv = 1.0f / s_tot;

#pragma unroll
  for (int df = 0; df < 4; ++df) {
    float4 ov;
    ov.x = o_acc[df][0] * inv;
    ov.y = o_acc[df][1] * inv;
    ov.z = o_acc[df][2] * inv;
    ov.w = o_acc[df][3] * inv;
    *(float4*)(Out + ((size_t)b * S_LEN + qrow) * D_DIM + h * HD + df * 16 + lhi * 4) = ov;
  }
}

// ---------------- launch ----------------

extern "C" void kernel_launch(void* const* d_in, const int* in_sizes, int n_in,
                              void* d_out, int out_size, void* d_ws, size_t ws_size,
                              hipStream_t stream) {
  (void)in_sizes; (void)n_in; (void)out_size; (void)ws_size;
  const float* hs   = (const float*)d_in[0];
  const float* mask = (const float*)d_in[1];
  const float* Wq   = (const float*)d_in[2];
  const float* bq   = (const float*)d_in[3];
  const float* Wk   = (const float*)d_in[4];
  const float* bk   = (const float*)d_in[5];
  const float* Wv   = (const float*)d_in[6];
  const float* bv   = (const float*)d_in[7];
  const float* pW1  = (const float*)d_in[8];
  const float* pb1  = (const float*)d_in[9];
  const float* gam  = (const float*)d_in[10];
  const float* bet  = (const float*)d_in[11];
  const float* mea  = (const float*)d_in[12];
  const float* var  = (const float*)d_in[13];
  const float* pW2  = (const float*)d_in[14];
  const float* pb2  = (const float*)d_in[15];
  float* out = (float*)d_out;

  const size_t MB = 1u << 20;
  char* ws = (char*)d_ws;
  unsigned short* hsb = (unsigned short*)(ws);            // 8 MB [4096][1024]
  unsigned short* wTq = (unsigned short*)(ws + 8 * MB);   // 2 MB  (wTq|wTk|wTv
  unsigned short* wTk = (unsigned short*)(ws + 10 * MB);  // 2 MB   must stay
  unsigned short* wTv = (unsigned short*)(ws + 12 * MB);  // 2 MB   contiguous!)
  unsigned short* Qb  = (unsigned short*)(ws + 14 * MB);  // 8 MB [32][2048][64]
  unsigned short* Kb  = (unsigned short*)(ws + 22 * MB);  // 8 MB [32][2048][64]
  unsigned short* Vtb = (unsigned short*)(ws + 30 * MB);  // 8 MB [32][64][2048]
  float* partial = (float*)(ws + 38 * MB);                // 1 MB [2*128][1024]
  float* pooledb = (float*)(ws + 39 * MB);                // 8 KB [2048]
  float* gateb   = (float*)(ws + 39 * MB + 16384);        // 128 B [32]

  // fused pool+cvt (256 blocks) | weight transpose (768 blocks) — independent
  prep_kernel<<<1024, 256, 0, stream>>>(hs, hsb, partial, Wq, Wk, Wv, wTq, wTk, wTv);
  pool_reduce<<<16, 128, 0, stream>>>(partial, pooledb);
  gate_kernel<<<1, 512, 0, stream>>>(pooledb, pW1, pb1, gam, bet, mea, var, pW2, pb2, gateb);

  // fused Q+K+V projection with gate-skip: N = 3072 over [wTq|wTk|wTv]
  proj_gemm3<<<768, 256, 0, stream>>>(hsb, wTq, bq, bk, bv, gateb, Qb, Kb, Vtb);

  attn_kernel<<<1024, 256, 0, stream>>>(Qb, Kb, Vtb, mask, gateb, out);
}